// Round 1
// baseline (4064.964 us; speedup 1.0000x reference)
//
#include <hip/hip_runtime.h>
#include <math.h>

#define H 16
#define S 2048
#define D 64
#define R 16        // rows per block
#define T 64        // j-tile width
#define NEGC -1.0e9f

__device__ __forceinline__ float softplus_f(float x) {
    // log(1 + exp(x)), stable
    return fmaxf(x, 0.0f) + log1pf(expf(-fabsf(x)));
}

__global__ __launch_bounds__(256) void sb_kernel(const float* __restrict__ q,
                                                 const float* __restrict__ k,
                                                 const float* __restrict__ v,
                                                 float* __restrict__ out)
{
    __shared__ float sQ[R][D + 4];   // padded: break bank conflicts on row-broadcast reads
    __shared__ float sK[T][D + 4];
    __shared__ float sV[T][D];
    __shared__ float sL[R][T + 1];   // logits tile -> reused as weights tile
    __shared__ float sCarry[R];

    const int t  = threadIdx.x;
    const int h  = blockIdx.x / (S / R);
    const int it = blockIdx.x % (S / R);
    const int i0 = it * R;

    const float* qh = q + (size_t)h * S * D;
    const float* kh = k + (size_t)h * S * D;
    const float* vh = v + (size_t)h * S * D;

    // load Q rows [i0, i0+R): R*D = 1024 floats = 256 float4, one per thread
    {
        const float4 qv = ((const float4*)(qh + i0 * D))[t];
        const int row = t >> 4;          // 4 float4 per row (D=64)
        const int col = (t & 15) * 4;
        sQ[row][col + 0] = qv.x;
        sQ[row][col + 1] = qv.y;
        sQ[row][col + 2] = qv.z;
        sQ[row][col + 3] = qv.w;
    }
    if (t < R) sCarry[t] = 0.0f;

    float acc[4] = {0.f, 0.f, 0.f, 0.f};
    const int d  = t & 63;
    const int ig = t >> 6;   // 0..3: row group for phase C

    __syncthreads();

    for (int jt = S / T - 1; jt >= 0; --jt) {
        const int j0 = jt * T;

        // ---- stage K,V tile (T*D = 4096 floats = 1024 float4; 4 per thread) ----
        {
            const float4* ks = (const float4*)(kh + j0 * D);
            const float4* vs = (const float4*)(vh + j0 * D);
            float4* vd = (float4*)(&sV[0][0]);
            #pragma unroll
            for (int r = 0; r < 4; ++r) {
                const int idx = t + 256 * r;       // flat float4 index
                const float4 kv = ks[idx];
                const int row = idx >> 4;          // 16 float4 per row
                const int col = (idx & 15) * 4;
                sK[row][col + 0] = kv.x;
                sK[row][col + 1] = kv.y;
                sK[row][col + 2] = kv.z;
                sK[row][col + 3] = kv.w;
                vd[idx] = vs[idx];                 // sV unpadded: direct float4
            }
        }
        __syncthreads();

        // ---- phase A: logits tile, R*T = 1024 entries, 4 per thread ----
        {
            const int li = t & 15;
            const int j1 = t >> 4;   // 0..15
            const float4* qa = (const float4*)(&sQ[li][0]);
            #pragma unroll
            for (int r = 0; r < 4; ++r) {
                const int jj = j1 + 16 * r;
                const float4* ka = (const float4*)(&sK[jj][0]);
                float s = 0.f;
                #pragma unroll
                for (int x = 0; x < 16; ++x) {
                    const float4 a = qa[x], b = ka[x];
                    s += a.x * b.x + a.y * b.y + a.z * b.z + a.w * b.w;
                }
                sL[li][jj] = s * 0.125f;
            }
        }
        __syncthreads();

        // ---- phase B: serial reverse scan per row (matches np.cumsum(flip) order) ----
        if (t < R) {
            float c = sCarry[t];
            const int i = i0 + t;
            for (int jj = T - 1; jj >= 0; --jj) {
                const float l = sL[t][jj];
                const float m = (j0 + jj > i) ? NEGC : 0.0f;
                c += (-softplus_f(l)) + m;               // log_sigmoid(-l) + mask
                const float z = 1.0f / (1.0f + expf(-l)) + m;
                sL[t][jj] = z * expf(c);                 // weight
            }
            sCarry[t] = c;
        }
        __syncthreads();

        // ---- phase C: out += W * V ----
        #pragma unroll
        for (int r = 0; r < 4; ++r) {
            const int i = ig + 4 * r;
            float a = acc[r];
            #pragma unroll 8
            for (int jj = 0; jj < T; ++jj) {
                a += sL[i][jj] * sV[jj][d];
            }
            acc[r] = a;
        }
        __syncthreads();
    }

    // ---- write out ----
    #pragma unroll
    for (int r = 0; r < 4; ++r) {
        const int i = i0 + ig + 4 * r;
        out[((size_t)h * S + i) * D + d] = acc[r];
    }
}

extern "C" void kernel_launch(void* const* d_in, const int* in_sizes, int n_in,
                              void* d_out, int out_size, void* d_ws, size_t ws_size,
                              hipStream_t stream) {
    const float* q = (const float*)d_in[0];
    const float* k = (const float*)d_in[1];
    const float* v = (const float*)d_in[2];
    float* out = (float*)d_out;
    dim3 grid(H * (S / R));
    sb_kernel<<<grid, 256, 0, stream>>>(q, k, v, out);
}

// Round 2
// 115.604 us; speedup vs baseline: 35.1629x; 35.1629x over previous
//
#include <hip/hip_runtime.h>
#include <math.h>

#define H 16
#define S 2048
#define D 64
#define NT 512            // threads in fused kernel
#define C (S / NT)        // logits per thread in scan phase = 4

__device__ __forceinline__ float softplus_f(float x) {
    // log(1 + exp(x)), stable
    return fmaxf(x, 0.0f) + log1pf(expf(-fabsf(x)));
}

// Zero the whole output (harness poisons it to 0xAA before every launch).
__global__ __launch_bounds__(512) void zero_kernel(float4* __restrict__ out) {
    const int idx = blockIdx.x * 512 + threadIdx.x;   // [0, 262144)
    const float4 z = make_float4(0.f, 0.f, 0.f, 0.f);
    out[idx]          = z;
    out[idx + 262144] = z;
}

// Compute the only nonzero rows: out[h, S-1, :] for each head.
// weights[j] = sigmoid(l_j) * exp( sum_{j' >= j} log_sigmoid(-l_{j'}) ),
// l_j = q[h,S-1,:] . k[h,j,:] / 8
__global__ __launch_bounds__(NT) void sb_lastrow_kernel(const float* __restrict__ q,
                                                        const float* __restrict__ k,
                                                        const float* __restrict__ v,
                                                        float* __restrict__ out)
{
    __shared__ float sQ[D];
    __shared__ float sL[S];            // logits, then (in-place) weights
    __shared__ float sS[NT + 1];       // suffix-scan buffer; sS[NT] = 0 sentinel
    __shared__ float sR[32][D + 4];    // GEMV reduction across 32 row-groups

    const int t = threadIdx.x;
    const int h = blockIdx.x;
    const float* qh = q + ((size_t)h * S + (S - 1)) * D;
    const float* kh = k + (size_t)h * S * D;
    const float* vh = v + (size_t)h * S * D;

    if (t < D) sQ[t] = qh[t];
    __syncthreads();

    // ---- phase L: logits l[j] = (q . k_j) * 0.125 ----
    #pragma unroll
    for (int r = 0; r < S / NT; ++r) {
        const int j = t + r * NT;
        const float4* kr = (const float4*)(kh + (size_t)j * D);
        float s = 0.f;
        #pragma unroll
        for (int x = 0; x < D / 4; ++x) {
            const float4 b = kr[x];
            s += sQ[4 * x + 0] * b.x + sQ[4 * x + 1] * b.y
               + sQ[4 * x + 2] * b.z + sQ[4 * x + 3] * b.w;
        }
        sL[j] = s * 0.125f;
    }
    __syncthreads();

    // ---- phase S: suffix scan of lb[j] = log_sigmoid(-l[j]) = -softplus(l[j]) ----
    float lv[C], lb[C];
    float cs = 0.f;
    #pragma unroll
    for (int jj = 0; jj < C; ++jj) {
        lv[jj] = sL[t * C + jj];
        lb[jj] = -softplus_f(lv[jj]);
        cs += lb[jj];
    }
    sS[t] = cs;
    if (t == 0) sS[NT] = 0.f;
    __syncthreads();
    // inclusive suffix scan over chunk sums: sS[t] <- sum_{u >= t} cs[u]
    for (int off = 1; off < NT; off <<= 1) {
        const float x = sS[t] + ((t + off < NT) ? sS[t + off] : 0.f);
        __syncthreads();
        sS[t] = x;
        __syncthreads();
    }
    // exclusive suffix (all chunks strictly after mine); sS[NT] == 0
    float c = sS[t + 1];
    #pragma unroll
    for (int jj = C - 1; jj >= 0; --jj) {
        c += lb[jj];   // running suffix sum including j itself
        sL[t * C + jj] = (1.f / (1.f + expf(-lv[jj]))) * expf(c);  // weight
    }
    __syncthreads();

    // ---- phase G: out_row[d] = sum_j w[j] * v[j][d] ----
    const int g  = t >> 4;        // 0..31: row group
    const int c4 = t & 15;        // float4 column (4 d's)
    float4 acc = make_float4(0.f, 0.f, 0.f, 0.f);
    for (int j = g; j < S; j += 32) {
        const float w = sL[j];
        const float4 vv = ((const float4*)(vh + (size_t)j * D))[c4];
        acc.x += w * vv.x; acc.y += w * vv.y; acc.z += w * vv.z; acc.w += w * vv.w;
    }
    *((float4*)&sR[g][c4 * 4]) = acc;
    __syncthreads();
    for (int off = 16; off >= 1; off >>= 1) {
        if (g < off) {
            float4 a = *((float4*)&sR[g][c4 * 4]);
            const float4 b = *((float4*)&sR[g + off][c4 * 4]);
            a.x += b.x; a.y += b.y; a.z += b.z; a.w += b.w;
            *((float4*)&sR[g][c4 * 4]) = a;
        }
        __syncthreads();
    }
    if (g == 0) {
        float4* orow = (float4*)(out + ((size_t)h * S + (S - 1)) * D);
        orow[c4] = *((float4*)&sR[0][c4 * 4]);
    }
}

extern "C" void kernel_launch(void* const* d_in, const int* in_sizes, int n_in,
                              void* d_out, int out_size, void* d_ws, size_t ws_size,
                              hipStream_t stream) {
    const float* q = (const float*)d_in[0];
    const float* k = (const float*)d_in[1];
    const float* v = (const float*)d_in[2];
    float* out = (float*)d_out;

    // 1) zero the full output (H*S*D = 2,097,152 floats = 524,288 float4)
    zero_kernel<<<dim3(512), dim3(512), 0, stream>>>((float4*)out);
    // 2) compute the only nonzero rows (i = S-1 per head)
    sb_lastrow_kernel<<<dim3(H), dim3(NT), 0, stream>>>(q, k, v, out);
}

// Round 3
// 81.011 us; speedup vs baseline: 50.1778x; 1.4270x over previous
//
#include <hip/hip_runtime.h>
#include <math.h>

#define H 16
#define S 2048
#define D 64
#define NEED_WS (H * S * sizeof(float))   // 128 KB logit buffer

__device__ __forceinline__ float softplus_f(float x) {
    return fmaxf(x, 0.0f) + log1pf(expf(-fabsf(x)));   // log(1+e^x), stable
}

// ---------------- kernel 1: logits for the last row of each head ----------------
// grid = H*8 blocks, 256 threads. Block (h, chunk) computes l[h][chunk*256 + t].
__global__ __launch_bounds__(256) void logits_kernel(const float* __restrict__ q,
                                                     const float* __restrict__ k,
                                                     float* __restrict__ ws_l)
{
    __shared__ float sQ[D];
    const int t = threadIdx.x;
    const int h = blockIdx.x >> 3;
    const int j = (blockIdx.x & 7) * 256 + t;

    const float* qh = q + ((size_t)h * S + (S - 1)) * D;
    if (t < D) sQ[t] = qh[t];
    __syncthreads();

    const float4* kr = (const float4*)(k + ((size_t)h * S + j) * D);
    float s = 0.f;
    #pragma unroll
    for (int x = 0; x < D / 4; ++x) {
        const float4 b = kr[x];
        s += sQ[4 * x + 0] * b.x + sQ[4 * x + 1] * b.y
           + sQ[4 * x + 2] * b.z + sQ[4 * x + 3] * b.w;
    }
    ws_l[(size_t)h * S + j] = s * 0.125f;
}

// ---------------- kernel 2: suffix scan (redundant per block) + partial GEMV ----
// grid = H*16 blocks, 256 threads. Block (h, c) owns j in [c*128, (c+1)*128).
__global__ __launch_bounds__(256) void scan_gemv_kernel(const float* __restrict__ ws_l,
                                                        const float* __restrict__ v,
                                                        float* __restrict__ out)
{
    __shared__ float sS[257];       // suffix-scan buffer + sentinel
    __shared__ float sW[128];       // this block's chunk of weights
    __shared__ float sRed[4][D];    // GEMV reduction

    const int t  = threadIdx.x;
    const int h  = blockIdx.x >> 4;
    const int c  = blockIdx.x & 15;
    const int j0 = c * 128;
    const float* lrow = ws_l + (size_t)h * S;
    const float* vh   = v + (size_t)h * S * D;

    // --- full-head suffix scan, 8 logits per thread ---
    float lv[8], lb[8];
    {
        const float4 a = ((const float4*)(lrow + t * 8))[0];
        const float4 b = ((const float4*)(lrow + t * 8))[1];
        lv[0]=a.x; lv[1]=a.y; lv[2]=a.z; lv[3]=a.w;
        lv[4]=b.x; lv[5]=b.y; lv[6]=b.z; lv[7]=b.w;
    }
    float cs = 0.f;
    #pragma unroll
    for (int i = 0; i < 8; ++i) { lb[i] = -softplus_f(lv[i]); cs += lb[i]; }
    sS[t] = cs;
    if (t == 0) sS[256] = 0.f;
    __syncthreads();
    for (int off = 1; off < 256; off <<= 1) {
        const float x = sS[t] + ((t + off < 256) ? sS[t + off] : 0.f);
        __syncthreads();
        sS[t] = x;
        __syncthreads();
    }
    // exclusive suffix for my 8, then weights for this block's chunk only
    if ((t >> 4) == c) {                      // threads c*16 .. c*16+15 own [j0, j0+128)
        float cr = sS[t + 1];
        float w[8];
        #pragma unroll
        for (int i = 7; i >= 0; --i) {
            cr += lb[i];
            w[i] = (1.f / (1.f + expf(-lv[i]))) * expf(cr);
        }
        const int base = t * 8 - j0;
        #pragma unroll
        for (int i = 0; i < 8; ++i) sW[base + i] = w[i];
    }
    __syncthreads();

    // --- partial GEMV: 4 j-groups x 64 d ---
    const int g = t >> 6;       // 0..3
    const int d = t & 63;
    float acc = 0.f;
    #pragma unroll 8
    for (int jj = g; jj < 128; jj += 4)
        acc += sW[jj] * vh[(size_t)(j0 + jj) * D + d];
    sRed[g][d] = acc;
    __syncthreads();
    if (g == 0) {
        const float tot = sRed[0][d] + sRed[1][d] + sRed[2][d] + sRed[3][d];
        atomicAdd(out + ((size_t)h * S + (S - 1)) * D + d, tot);
    }
}

// ---------------- fallback (ws too small): round-2 single-block-per-head ----------
__global__ __launch_bounds__(512) void sb_lastrow_kernel(const float* __restrict__ q,
                                                         const float* __restrict__ k,
                                                         const float* __restrict__ v,
                                                         float* __restrict__ out)
{
    __shared__ float sQ[D];
    __shared__ float sL[S];
    __shared__ float sS[513];
    __shared__ float sR[32][D + 4];

    const int t = threadIdx.x;
    const int h = blockIdx.x;
    const float* qh = q + ((size_t)h * S + (S - 1)) * D;
    const float* kh = k + (size_t)h * S * D;
    const float* vh = v + (size_t)h * S * D;

    if (t < D) sQ[t] = qh[t];
    __syncthreads();
    #pragma unroll
    for (int r = 0; r < S / 512; ++r) {
        const int j = t + r * 512;
        const float4* kr = (const float4*)(kh + (size_t)j * D);
        float s = 0.f;
        #pragma unroll
        for (int x = 0; x < D / 4; ++x) {
            const float4 b = kr[x];
            s += sQ[4*x+0]*b.x + sQ[4*x+1]*b.y + sQ[4*x+2]*b.z + sQ[4*x+3]*b.w;
        }
        sL[j] = s * 0.125f;
    }
    __syncthreads();
    float lv[4], lb[4];
    float cs = 0.f;
    #pragma unroll
    for (int i = 0; i < 4; ++i) {
        lv[i] = sL[t * 4 + i];
        lb[i] = -softplus_f(lv[i]);
        cs += lb[i];
    }
    sS[t] = cs;
    if (t == 0) sS[512] = 0.f;
    __syncthreads();
    for (int off = 1; off < 512; off <<= 1) {
        const float x = sS[t] + ((t + off < 512) ? sS[t + off] : 0.f);
        __syncthreads();
        sS[t] = x;
        __syncthreads();
    }
    float cr = sS[t + 1];
    #pragma unroll
    for (int i = 3; i >= 0; --i) {
        cr += lb[i];
        sL[t * 4 + i] = (1.f / (1.f + expf(-lv[i]))) * expf(cr);
    }
    __syncthreads();
    const int g  = t >> 4;
    const int c4 = t & 15;
    float4 acc = make_float4(0.f, 0.f, 0.f, 0.f);
    for (int j = g; j < S; j += 32) {
        const float w = sL[j];
        const float4 vv = ((const float4*)(vh + (size_t)j * D))[c4];
        acc.x += w*vv.x; acc.y += w*vv.y; acc.z += w*vv.z; acc.w += w*vv.w;
    }
    *((float4*)&sR[g][c4 * 4]) = acc;
    __syncthreads();
    for (int off = 16; off >= 1; off >>= 1) {
        if (g < off) {
            float4 a = *((float4*)&sR[g][c4 * 4]);
            const float4 b = *((float4*)&sR[g + off][c4 * 4]);
            a.x += b.x; a.y += b.y; a.z += b.z; a.w += b.w;
            *((float4*)&sR[g][c4 * 4]) = a;
        }
        __syncthreads();
    }
    if (g == 0)
        ((float4*)(out + ((size_t)h * S + (S - 1)) * D))[c4] = *((float4*)&sR[0][c4 * 4]);
}

extern "C" void kernel_launch(void* const* d_in, const int* in_sizes, int n_in,
                              void* d_out, int out_size, void* d_ws, size_t ws_size,
                              hipStream_t stream) {
    const float* q = (const float*)d_in[0];
    const float* k = (const float*)d_in[1];
    const float* v = (const float*)d_in[2];
    float* out = (float*)d_out;

    // rows 0..S-2 of every head are exactly zero (masked -1e9 terms inside the
    // reverse-cumsum underflow exp() to +0.0 in fp32 for any data) -> memset all,
    // then compute only the last row per head.
    hipMemsetAsync(out, 0, (size_t)H * S * D * sizeof(float), stream);

    if (ws_size >= NEED_WS) {
        float* ws_l = (float*)d_ws;
        logits_kernel<<<dim3(H * 8), dim3(256), 0, stream>>>(q, k, ws_l);
        scan_gemv_kernel<<<dim3(H * 16), dim3(256), 0, stream>>>(ws_l, v, out);
    } else {
        sb_lastrow_kernel<<<dim3(H), dim3(512), 0, stream>>>(q, k, v, out);
    }
}